// Round 6
// baseline (215.710 us; speedup 1.0000x reference)
//
#include <hip/hip_runtime.h>

typedef unsigned int uint;
typedef unsigned short ushort;

#define IN_C 128
#define HID  32

// ---- f16 helpers (fp32 accumulate everywhere; RNE on store) ---------------
__device__ __forceinline__ uint f2h2(float a, float b) {
    _Float16 ha = (_Float16)a, hb = (_Float16)b;
    unsigned short ua = __builtin_bit_cast(unsigned short, ha);
    unsigned short ub = __builtin_bit_cast(unsigned short, hb);
    return (uint)ua | ((uint)ub << 16);
}
// acc += f16_lo(pk) * v  -- single full-rate VOP3P v_fma_mix_f32, no unpack
__device__ __forceinline__ void fma_lo(float& acc, uint pk, float v) {
    asm("v_fma_mix_f32 %0, %1, %2, %0 op_sel:[0,0,0] op_sel_hi:[1,0,0]"
        : "+v"(acc) : "v"(pk), "v"(v));
}
// acc += f16_hi(pk) * v
__device__ __forceinline__ void fma_hi(float& acc, uint pk, float v) {
    asm("v_fma_mix_f32 %0, %1, %2, %0 op_sel:[1,0,0] op_sel_hi:[1,0,0]"
        : "+v"(acc) : "v"(pk), "v"(v));
}

// async global->LDS, 16 B per lane: lane i's 16B source -> ldsBase + i*16
typedef const __attribute__((address_space(1))) void* gas1_t;
typedef __attribute__((address_space(3))) void*       las3_t;
__device__ __forceinline__ void glds16(const void* g, void* l) {
    __builtin_amdgcn_global_load_lds((gas1_t)g, (las3_t)l, 16, 0, 0);
}

// ---------------------------------------------------------------------------
// K1: fused prep (unchanged).
// ---------------------------------------------------------------------------
__global__ void prep_kernel(const float* __restrict__ x,
                            const float* __restrict__ w,
                            ushort* __restrict__ r0,
                            const int* __restrict__ a1r, int E1, int* __restrict__ ip1,
                            const int* __restrict__ a2r, int E2, int* __restrict__ ip2,
                            const int* __restrict__ a2c, const float* __restrict__ a2v,
                            float* __restrict__ dummy,
                            int n, int nbE, int nbI, int nbT) {
    __shared__ float wl[IN_C * HID];
    const int tid = threadIdx.x;
    if (blockIdx.x < nbE) {
        for (int i = tid; i < IN_C * HID; i += blockDim.x) wl[i] = w[i];
        __syncthreads();
        const int row = blockIdx.x * 16 + tid / 16;
        const int h0  = (tid % 16) * 2;
        if (row >= n) return;
        const float4* xr = (const float4*)(x + (size_t)row * IN_C);
        float a0 = 0.f, a1 = 0.f;
#pragma unroll
        for (int k4 = 0; k4 < IN_C / 4; ++k4) {
            float4 xv = xr[k4];
            a0 += xv.x * wl[(4*k4+0)*HID + h0];  a1 += xv.x * wl[(4*k4+0)*HID + h0+1];
            a0 += xv.y * wl[(4*k4+1)*HID + h0];  a1 += xv.y * wl[(4*k4+1)*HID + h0+1];
            a0 += xv.z * wl[(4*k4+2)*HID + h0];  a1 += xv.z * wl[(4*k4+2)*HID + h0+1];
            a0 += xv.w * wl[(4*k4+3)*HID + h0];  a1 += xv.w * wl[(4*k4+3)*HID + h0+1];
        }
        uint p = f2h2(fmaxf(a0, 0.f), fmaxf(a1, 0.f));
        ((uint*)r0)[(size_t)row * 16 + (tid % 16)] = p;
    } else if (blockIdx.x < nbE + nbI) {
        const int i = (blockIdx.x - nbE) * 256 + tid;
        if (i > n) return;
        int lo = 0, hi = E1;
        while (lo < hi) { int m = (lo + hi) >> 1; if (a1r[m] < i) lo = m + 1; else hi = m; }
        ip1[i] = lo;
        lo = 0; hi = E2;
        while (lo < hi) { int m = (lo + hi) >> 1; if (a2r[m] < i) lo = m + 1; else hi = m; }
        ip2[i] = lo;
    } else {
        const int t = (blockIdx.x - nbE - nbI) * 256 + tid;
        const int stride = nbT * 256;
        const int total4 = E2 / 4;
        const float4* c4 = (const float4*)a2c;
        const float4* v4 = (const float4*)a2v;
        float s = 0.f;
        for (int i = t; i < total4; i += stride) {
            float4 u = c4[i], v = v4[i];
            s += u.x + u.y + u.z + u.w + v.x + v.y + v.z + v.w;
        }
        if (s == 123.456f) dummy[0] = s;   // never true in practice; defeats DCE
    }
}

// ---------------------------------------------------------------------------
// K2: fused-level SpMM + ReLU, f16 features / fp32 accumulate (v_fma_mix).
// R6: heavy (A2) path = double-buffered LDS chunk stream (T3+T4 pattern).
// Two consecutive rows per wave -> one flat chunk sequence; per iteration:
//   stage(chunk j+1 -> buf^1)  [2x global_load_lds]
//   s_waitcnt vmcnt(2)         [chunk j ready; j+1 STAYS IN FLIGHT]
//   consume(chunk j from buf)  [ds_read_b128 edges -> L2 gathers -> fma_mix]
// Retire is in issue order and every gather is consumed within its chunk, so
// outstanding at the wait is exactly {stage j, stage j+1} -> the counted wait
// is static and never drains the pipeline (R5 paid a full vmcnt(0) LLC stall
// per chunk). Stage latency exposed once per row-pair only.
// Last <=3 edges of the whole array handled direct-global (E2%4 guard).
// Light (A1) path = R2 depth-1 pipeline. Blocks [0,nbH)=A2; rest=A1.
// ---------------------------------------------------------------------------
template <int C, int ROWSL>
__global__ __launch_bounds__(256) void spmm_level(
        const int* __restrict__ ip1, const int* __restrict__ col1,
        const float* __restrict__ val1, int E1,
        const int* __restrict__ ip2, const int* __restrict__ col2,
        const float* __restrict__ val2, int E2,
        const ushort* __restrict__ xin, ushort* __restrict__ out,
        int n, int nbH) {
    constexpr int L = C / 8;                 // feature lanes per row (4 or 8)
    __shared__ __align__(16) int   scol[4][2][256];
    __shared__ __align__(16) float sval[4][2][256];

    const int lane = threadIdx.x & 63;
    const int wave = threadIdx.x >> 6;
    (void)E1;

    int bid = blockIdx.x;
    if (bid < nbH) {
        // ---------------- heavy path: A2, two rows per wave ----------------
        constexpr int W = 64 / L;            // edge ways (16 for C=32, 8 for C=64)
        const int fl  = lane % L;
        const int way = lane / L;
        const uint flo = (uint)fl * 16u;

        auto gat = [&](uint c) -> uint4 {
            return *(const uint4*)((const char*)xin + (c * (uint)(2 * C) + flo));
        };
        float accA[8], accB[8];
#pragma unroll
        for (int j = 0; j < 8; ++j) { accA[j] = 0.f; accB[j] = 0.f; }
        auto fmadd = [&](float (&ac)[8], const uint4& u, float v) {
            fma_lo(ac[0], u.x, v); fma_hi(ac[1], u.x, v);
            fma_lo(ac[2], u.y, v); fma_hi(ac[3], u.y, v);
            fma_lo(ac[4], u.z, v); fma_hi(ac[5], u.z, v);
            fma_lo(ac[6], u.w, v); fma_hi(ac[7], u.w, v);
        };

        const int rowA = (bid * 4 + wave) * 2;
        const int rowB = rowA + 1;
        if (rowA >= n) return;
        const bool hasB = (rowB < n);

        const int sA = ip2[rowA];
        const int eA = ip2[rowA + 1];
        const int sB = eA;                       // consecutive rows share boundary
        const int eB = hasB ? ip2[rowB + 1] : eA;

        const int cut      = E2 & ~3;            // edges >= cut: direct-global
        const int clampOff = (E2 - 4) & ~3;      // stage clamp (aligned, in-bounds)

        // heads (unaligned starts) + global-array tail, direct from global
        int svA = (sA + 3) & ~3; if (svA > eA) svA = eA;
        int svB = (sB + 3) & ~3; if (svB > eB) svB = eB;
        for (int idx = sA + way; idx < svA; idx += W)
            fmadd(accA, gat((uint)col2[idx]), val2[idx]);
        for (int idx = sB + way; idx < svB; idx += W)
            fmadd(accB, gat((uint)col2[idx]), val2[idx]);
        int eeA = eA, eeB = eB;
        if (eeA > cut) {
            int st = (svA > cut) ? svA : cut;
            for (int idx = st + way; idx < eeA; idx += W)
                fmadd(accA, gat((uint)col2[idx]), val2[idx]);
            eeA = st;
        }
        if (eeB > cut) {
            int st = (svB > cut) ? svB : cut;
            for (int idx = st + way; idx < eeB; idx += W)
                fmadd(accB, gat((uint)col2[idx]), val2[idx]);
            eeB = st;
        }

        const int ncA = (eeA - svA + 255) >> 8;
        const int ncB = (eeB - svB + 255) >> 8;
        const int nc  = ncA + ncB;

        auto chunkBase = [&](int j) -> int {
            int jj = (j < nc) ? j : (nc - 1);
            return (jj < ncA) ? (svA + (jj << 8)) : (svB + ((jj - ncA) << 8));
        };
        auto stage = [&](int buf, int base) {
            int so = base + lane * 4; if (so > clampOff) so = clampOff;
            glds16(col2 + so, &scol[wave][buf][0]);
            glds16(val2 + so, &sval[wave][buf][0]);
        };
        auto consume = [&](float (&ac)[8], const int* mc, const float* mv, int cnt) {
            const int nb = cnt / (4 * W);
            for (int b = 0; b < nb; ++b) {
                const int o = (b * W + way) * 4;
                const int4   cc = *(const int4*)  (mc + o);
                const float4 vv = *(const float4*)(mv + o);
                const uint4 g0 = gat((uint)cc.x), g1 = gat((uint)cc.y),
                            g2 = gat((uint)cc.z), g3 = gat((uint)cc.w);
                fmadd(ac, g0, vv.x); fmadd(ac, g1, vv.y);
                fmadd(ac, g2, vv.z); fmadd(ac, g3, vv.w);
            }
            for (int k = nb * 4 * W + way; k < cnt; k += W)
                fmadd(ac, gat((uint)mc[k]), mv[k]);
        };

        if (nc > 0) {
            stage(0, chunkBase(0));
            for (int j = 0; j < nc; ++j) {
                stage((j + 1) & 1, chunkBase(j + 1));   // dummy at j=nc-1 (never read)
                asm volatile("s_waitcnt vmcnt(2)" ::: "memory");
                const bool isA = (j < ncA);
                const int base = isA ? (svA + (j << 8)) : (svB + ((j - ncA) << 8));
                const int end  = isA ? eeA : eeB;
                int cnt = end - base; if (cnt > 256) cnt = 256;
                const int*   mc = &scol[wave][j & 1][0];
                const float* mv = &sval[wave][j & 1][0];
                if (isA) consume(accA, mc, mv, cnt);
                else     consume(accB, mc, mv, cnt);
            }
        }

        // cross-way reduction (ways span the full wave) + store
        auto redstore = [&](float (&ac)[8], int row) {
#pragma unroll
            for (int m = L; m < 64; m <<= 1)
#pragma unroll
                for (int j = 0; j < 8; ++j) ac[j] += __shfl_xor(ac[j], m, 64);
            if (way == 0) {
                uint4 p;
                p.x = f2h2(fmaxf(ac[0], 0.f), fmaxf(ac[1], 0.f));
                p.y = f2h2(fmaxf(ac[2], 0.f), fmaxf(ac[3], 0.f));
                p.z = f2h2(fmaxf(ac[4], 0.f), fmaxf(ac[5], 0.f));
                p.w = f2h2(fmaxf(ac[6], 0.f), fmaxf(ac[7], 0.f));
                *(uint4*)(out + (size_t)row * (2 * C) + C + fl * 8) = p;
            }
        };
        redstore(accA, rowA);
        if (hasB) redstore(accB, rowB);
    } else {
        // ---------------- light path: A1 (R2 structure) --------------------
        bid -= nbH;
        constexpr int SUBL = 64 / ROWSL;
        constexpr int WL   = SUBL / L;
        const int sub = lane / SUBL;
        const int li  = lane % SUBL;
        const int fl  = li % L;
        const int way = li / L;
        const uint flo = (uint)fl * 16u;

        auto gat = [&](uint c) -> uint4 {
            return *(const uint4*)((const char*)xin + (c * (uint)(2 * C) + flo));
        };
        float acc[8];
#pragma unroll
        for (int j = 0; j < 8; ++j) acc[j] = 0.f;
        auto fmadd = [&](const uint4& u, float v) {
            fma_lo(acc[0], u.x, v); fma_hi(acc[1], u.x, v);
            fma_lo(acc[2], u.y, v); fma_hi(acc[3], u.y, v);
            fma_lo(acc[4], u.z, v); fma_hi(acc[5], u.z, v);
            fma_lo(acc[6], u.w, v); fma_hi(acc[7], u.w, v);
        };

        const int row = (bid * 4 + wave) * ROWSL + sub;
        if (row >= n) return;
        const int s = ip1[row];
        const int e = ip1[row + 1];
        int idx0 = s + way;
        if (idx0 < e) {
            int c0 = col1[idx0]; float v0 = val1[idx0];
            int idx1 = idx0 + WL;
            int c1 = 0; float v1 = 0.f;
            if (idx1 < e) { c1 = col1[idx1]; v1 = val1[idx1]; }
            uint4 g0 = gat((uint)c0);
            while (true) {
                int idx2 = idx1 + WL;
                int c2 = 0; float v2 = 0.f;
                if (idx2 < e) { c2 = col1[idx2]; v2 = val1[idx2]; }
                uint4 g1 = gat((uint)c1);
                fmadd(g0, v0);
                if (idx1 >= e) break;
                g0 = g1; c1 = c2; v0 = v1; v1 = v2;
                idx1 = idx2;
            }
        }
#pragma unroll
        for (int m = L; m < SUBL; m <<= 1)
#pragma unroll
            for (int j = 0; j < 8; ++j) acc[j] += __shfl_xor(acc[j], m, 64);
        if (way == 0) {
            uint4 p;
            p.x = f2h2(fmaxf(acc[0], 0.f), fmaxf(acc[1], 0.f));
            p.y = f2h2(fmaxf(acc[2], 0.f), fmaxf(acc[3], 0.f));
            p.z = f2h2(fmaxf(acc[4], 0.f), fmaxf(acc[5], 0.f));
            p.w = f2h2(fmaxf(acc[6], 0.f), fmaxf(acc[7], 0.f));
            *(uint4*)(out + (size_t)row * (2 * C) + fl * 8) = p;
        }
    }
}

// ---------------------------------------------------------------------------
// K3: out = [r0 | r1 | r2] @ w_classify  (f16 features via v_fma_mix,
// fp32 weights in LDS)
// ---------------------------------------------------------------------------
#define CDIM 224
#define OUT_C 16
__global__ void classify_kernel(const ushort* __restrict__ r0,
                                const ushort* __restrict__ r1,
                                const ushort* __restrict__ r2,
                                const float* __restrict__ w,
                                float* __restrict__ out, int n) {
    __shared__ float wl[CDIM * OUT_C];
    const int tid = threadIdx.x;
    for (int i = tid; i < CDIM * OUT_C; i += blockDim.x) wl[i] = w[i];
    __syncthreads();
    const int row = blockIdx.x * 16 + tid / 16;
    const int o   = tid % 16;
    if (row >= n) return;
    float acc = 0.f;

    const uint4* a = (const uint4*)(r0 + (size_t)row * 32);
#pragma unroll
    for (int q = 0; q < 4; ++q) {
        uint4 u = a[q]; int j = q * 8;
        fma_lo(acc, u.x, wl[(j+0)*OUT_C + o]);  fma_hi(acc, u.x, wl[(j+1)*OUT_C + o]);
        fma_lo(acc, u.y, wl[(j+2)*OUT_C + o]);  fma_hi(acc, u.y, wl[(j+3)*OUT_C + o]);
        fma_lo(acc, u.z, wl[(j+4)*OUT_C + o]);  fma_hi(acc, u.z, wl[(j+5)*OUT_C + o]);
        fma_lo(acc, u.w, wl[(j+6)*OUT_C + o]);  fma_hi(acc, u.w, wl[(j+7)*OUT_C + o]);
    }
    const uint4* b = (const uint4*)(r1 + (size_t)row * 64);
#pragma unroll
    for (int q = 0; q < 8; ++q) {
        uint4 u = b[q]; int j = 32 + q * 8;
        fma_lo(acc, u.x, wl[(j+0)*OUT_C + o]);  fma_hi(acc, u.x, wl[(j+1)*OUT_C + o]);
        fma_lo(acc, u.y, wl[(j+2)*OUT_C + o]);  fma_hi(acc, u.y, wl[(j+3)*OUT_C + o]);
        fma_lo(acc, u.z, wl[(j+4)*OUT_C + o]);  fma_hi(acc, u.z, wl[(j+5)*OUT_C + o]);
        fma_lo(acc, u.w, wl[(j+6)*OUT_C + o]);  fma_hi(acc, u.w, wl[(j+7)*OUT_C + o]);
    }
    const uint4* c = (const uint4*)(r2 + (size_t)row * 128);
#pragma unroll
    for (int q = 0; q < 16; ++q) {
        uint4 u = c[q]; int j = 96 + q * 8;
        fma_lo(acc, u.x, wl[(j+0)*OUT_C + o]);  fma_hi(acc, u.x, wl[(j+1)*OUT_C + o]);
        fma_lo(acc, u.y, wl[(j+2)*OUT_C + o]);  fma_hi(acc, u.y, wl[(j+3)*OUT_C + o]);
        fma_lo(acc, u.z, wl[(j+4)*OUT_C + o]);  fma_hi(acc, u.z, wl[(j+5)*OUT_C + o]);
        fma_lo(acc, u.w, wl[(j+6)*OUT_C + o]);  fma_hi(acc, u.w, wl[(j+7)*OUT_C + o]);
    }
    out[(size_t)row * OUT_C + o] = acc;
}

// ---------------------------------------------------------------------------
extern "C" void kernel_launch(void* const* d_in, const int* in_sizes, int n_in,
                              void* d_out, int out_size, void* d_ws, size_t ws_size,
                              hipStream_t stream) {
    const float* x   = (const float*)d_in[0];
    const float* we  = (const float*)d_in[1];
    const float* wc  = (const float*)d_in[2];
    const int*   a1r = (const int*)  d_in[3];
    const int*   a1c = (const int*)  d_in[4];
    const float* a1v = (const float*)d_in[5];
    const int*   a2r = (const int*)  d_in[6];
    const int*   a2c = (const int*)  d_in[7];
    const float* a2v = (const float*)d_in[8];
    float* out = (float*)d_out;

    const int E1 = in_sizes[3];
    const int E2 = in_sizes[6];
    const int n  = in_sizes[0] / IN_C;   // 20000

    // Workspace (f16 features): r0[n*32] r1[n*64] r2[n*128], ip1/ip2, dummy
    ushort* r0 = (ushort*)d_ws;
    ushort* r1 = r0 + (size_t)n * 32;
    ushort* r2 = r1 + (size_t)n * 64;
    int*   ip1 = (int*)(r2 + (size_t)n * 128);
    int*   ip2 = ip1 + (n + 1);
    float* dummy = (float*)(ip2 + (n + 2));

    // 1) fused embed + indptr + A2 edge-list warm-touch
    {
        const int nbE = (n + 15) / 16;
        const int nbI = (n + 1 + 255) / 256;
        const int nbT = 512;
        prep_kernel<<<nbE + nbI + nbT, 256, 0, stream>>>(
            x, we, r0, a1r, E1, ip1, a2r, E2, ip2, a2c, a2v, dummy,
            n, nbE, nbI, nbT);
    }

    // 2) level 1: r1 = relu([A1 r0 | A2 r0]); C=32
    //    heavy: 2 rows/wave (8 rows/block); light: ROWSL=2 (8 rows/block)
    {
        const int nbH = (n + 7) / 8;
        const int nbL = (n + 7) / 8;
        spmm_level<32, 2><<<nbH + nbL, 256, 0, stream>>>(
            ip1, a1c, a1v, E1, ip2, a2c, a2v, E2, r0, r1, n, nbH);
    }
    // 3) level 2: r2 = relu([A1 r1 | A2 r1]); C=64
    //    heavy: 2 rows/wave (8 rows/block); light: ROWSL=1 (4 rows/block)
    {
        const int nbH = (n + 7) / 8;
        const int nbL = (n + 3) / 4;
        spmm_level<64, 1><<<nbH + nbL, 256, 0, stream>>>(
            ip1, a1c, a1v, E1, ip2, a2c, a2v, E2, r1, r2, n, nbH);
    }

    // 4) fused concat + classify
    classify_kernel<<<(n + 15) / 16, 256, 0, stream>>>(r0, r1, r2, wc, out, n);
}